// Round 5
// baseline (204.204 us; speedup 1.0000x reference)
//
#include <hip/hip_runtime.h>

// UFO linear attention, MI355X (gfx950). B=8, N=4096, C=512, H=8, DK=DV=64.
//
// R8: BK=32 + full LDS double-buffer + ONE __syncthreads per K-tile.
// R7 learned: MfmaUtil is capped by per-wave VALU (fp32->bf16 f2b ~7
// instr/elem, 2x redundant) and the 256-B-row fp32 A tile bank-conflicts.
// Now: A (fp32 path) is reg-staged and packed ONCE per element with
// add+v_perm half-up rounding (3 VALU / 2 elems); LDS holds bf16 only
// (128x32 = 8 KB per operand, proven conflict-free row geometry);
// 2x(A+B) buffers = 32 KB -> 4 blocks/CU potential. Pipeline per tile:
// issue A-loads + B gl_lds for t+1, COMPUTE(t), pack+ds_write A(t+1),
// sync. Loads fly under compute; single drain+barrier per tile.

typedef __attribute__((ext_vector_type(4))) float f32x4;
typedef __attribute__((ext_vector_type(8))) short s16x8;
typedef __attribute__((ext_vector_type(4))) unsigned short u16x4;
typedef __attribute__((ext_vector_type(2))) unsigned u32x2;

#define DEVFN __device__ __forceinline__

DEVFN unsigned short f2b(float f) {  // fp32 -> bf16 RNE
  union { float f; unsigned u; } un; un.f = f;
  unsigned r = un.u + 0x7fffu + ((un.u >> 16) & 1u);
  return (unsigned short)(r >> 16);
}
DEVFN float b2f(unsigned short us) {
  union { unsigned u; float f; } un; un.u = ((unsigned)us) << 16;
  return un.f;
}
// pack two fp32 -> dword of 2 bf16 (round-half-up): 2 adds + 1 v_perm
DEVFN unsigned pk2(float x0, float x1) {
  union { float f; unsigned u; } a, b;
  a.f = x0; b.f = x1;
  return __builtin_amdgcn_perm(b.u + 0x8000u, a.u + 0x8000u, 0x07060302u);
}

// async global->LDS, 16 B per lane; lds dest = wave-uniform base + lane*16
DEVFN void gl_lds16(const void* g, void* l) {
  __builtin_amdgcn_global_load_lds(
      (const __attribute__((address_space(1))) unsigned*)g,
      (__attribute__((address_space(3))) unsigned*)l, 16, 0, 0);
}

// ---------------------------------------------------------------------------
// Core GEMM: C[m][n] = sum_k A[m][k]*Bt[n][k] + bias[n]; optional fused
// head-norm. M = grid, N = K = 512. 128x128 tile, BK=32 (16 K-tiles),
// 4 waves. LDS: As[2][8KB] + Bs[2][8KB] bf16, 64-B rows, 4-slot XOR swz.
// ---------------------------------------------------------------------------
template <bool AF32, typename CT>
DEVFN void gemm_core(const void* Ain, const unsigned short* Bt,
                     const float* bias, CT* C, bool qnorm, const float* gamma,
                     int bx, int by) {
  constexpr int NN = 512;
  __shared__ __align__(16) char AsL[2][8192];
  __shared__ __align__(16) char BsL[2][8192];
  const int tid = threadIdx.x, lane = tid & 63, wid = tid >> 6;
  const int wm = (wid >> 1) * 64, wn = (wid & 1) * 64;
  const int r = lane & 15, g = lane >> 4;

  // B gl_lds source (pre-swizzled; chunk c = wid*2+q covers rows c*16..+16;
  // lane l -> row c*16+(l>>2), content-slot (l&3)^((l>>3)&3)).
  const char* Bsrc = (const char*)Bt +
      (long)(by * 128 + wid * 32 + (lane >> 2)) * 1024 +
      (((lane & 3) ^ ((lane >> 3) & 3)) * 16);

  // A sources
  const char* AsrcR = nullptr;  // fp32 reg-staging: thread t -> row t>>1
  const char* AsrcG = nullptr;  // bf16 gl_lds (same pattern as B)
  int awr[4];                   // swizzled ds_write byte offsets (fp32 path)
  if constexpr (AF32) {
    AsrcR = (const char*)Ain + (long)(bx * 128 + (tid >> 1)) * 2048 +
            (tid & 1) * 64;
    const int row = tid >> 1, rs = (row >> 1) & 3;
#pragma unroll
    for (int j = 0; j < 4; ++j) {
      int p = (tid & 1) * 4 + j;  // 8-B piece index within 64-B row
      awr[j] = row * 64 + ((((p >> 1) ^ rs) << 4) | ((p & 1) * 8));
    }
  } else {
    AsrcG = (const char*)Ain +
        (long)(bx * 128 + wid * 32 + (lane >> 2)) * 1024 +
        (((lane & 3) ^ ((lane >> 3) & 3)) * 16);
  }

  f32x4 PA[4];
  f32x4 acc[4][4] = {};

#define ISSUE_A(KT)                                                            \
  {                                                                            \
    _Pragma("unroll") for (int j = 0; j < 4; ++j)                              \
        PA[j] = *reinterpret_cast<const f32x4*>(AsrcR + (KT)*128 + j * 16);    \
  }

#define PACK_WRITE_A(BUF)                                                      \
  {                                                                            \
    _Pragma("unroll") for (int j = 0; j < 4; ++j) {                            \
      u32x2 w;                                                                 \
      w[0] = pk2(PA[j][0], PA[j][1]);                                          \
      w[1] = pk2(PA[j][2], PA[j][3]);                                          \
      *reinterpret_cast<u32x2*>(AsL[BUF] + awr[j]) = w;                        \
    }                                                                          \
  }

#define STAGE_B(BUF, KT)                                                       \
  {                                                                            \
    _Pragma("unroll") for (int q = 0; q < 2; ++q)                              \
        gl_lds16(Bsrc + q * 16384 + (KT)*64,                                   \
                 BsL[BUF] + (wid * 2 + q) * 1024);                             \
  }

#define STAGE_AG(BUF, KT)                                                      \
  {                                                                            \
    _Pragma("unroll") for (int q = 0; q < 2; ++q)                              \
        gl_lds16(AsrcG + q * 16384 + (KT)*64,                                  \
                 AsL[BUF] + (wid * 2 + q) * 1024);                             \
  }

#define COMPUTE(BUF)                                                           \
  {                                                                            \
    s16x8 a[4], b[4];                                                          \
    _Pragma("unroll") for (int i = 0; i < 4; ++i) {                            \
      int ar = wm + i * 16 + r;                                                \
      a[i] = *reinterpret_cast<const s16x8*>(                                  \
          AsL[BUF] + ar * 64 + ((g ^ ((ar >> 1) & 3)) << 4));                  \
      int br = wn + i * 16 + r;                                                \
      b[i] = *reinterpret_cast<const s16x8*>(                                  \
          BsL[BUF] + br * 64 + ((g ^ ((br >> 1) & 3)) << 4));                  \
    }                                                                          \
    _Pragma("unroll") for (int i = 0; i < 4; ++i)                              \
        _Pragma("unroll") for (int j = 0; j < 4; ++j) acc[i][j] =              \
        __builtin_amdgcn_mfma_f32_16x16x32_bf16(a[i], b[j], acc[i][j], 0, 0,   \
                                                0);                            \
  }

#define STEP(CUR, NXT, KT)                                                     \
  if constexpr (AF32) { ISSUE_A(KT) }                                          \
  STAGE_B(NXT, KT)                                                             \
  if constexpr (!AF32) { STAGE_AG(NXT, KT) }                                   \
  COMPUTE(CUR)                                                                 \
  if constexpr (AF32) { PACK_WRITE_A(NXT) }                                    \
  __syncthreads();

  // prologue: tile 0 -> buf 0
  if constexpr (AF32) { ISSUE_A(0) PACK_WRITE_A(0) } else { STAGE_AG(0, 0) }
  STAGE_B(0, 0)
  __syncthreads();

  STEP(0, 1, 1)
  STEP(1, 0, 2)
  STEP(0, 1, 3)
  STEP(1, 0, 4)
  STEP(0, 1, 5)
  STEP(1, 0, 6)
  STEP(0, 1, 7)
  STEP(1, 0, 8)
  STEP(0, 1, 9)
  STEP(1, 0, 10)
  STEP(0, 1, 11)
  STEP(1, 0, 12)
  STEP(0, 1, 13)
  STEP(1, 0, 14)
  STEP(0, 1, 15)
  COMPUTE(1)

#undef ISSUE_A
#undef PACK_WRITE_A
#undef STAGE_B
#undef STAGE_AG
#undef COMPUTE
#undef STEP

  // ---- epilogue (C/D layout: col=lane&15, row=(lane>>4)*4+ii) ----
  const int crow0 = bx * 128 + wm + g * 4;
  const int ccol0 = by * 128 + wn + r;
#pragma unroll
  for (int j = 0; j < 4; ++j) {
    float bv = bias[ccol0 + j * 16];
#pragma unroll
    for (int i = 0; i < 4; ++i)
#pragma unroll
      for (int ii = 0; ii < 4; ++ii) acc[i][j][ii] += bv;
  }
  if (qnorm) {  // wave's 64 cols == one head; L2-norm over them per row
    const int h = (by * 128 + wn) >> 6;
    const float gam = gamma[h];
#pragma unroll
    for (int i = 0; i < 4; ++i)
#pragma unroll
      for (int ii = 0; ii < 4; ++ii) {
        float s = 0.f;
#pragma unroll
        for (int j = 0; j < 4; ++j) s += acc[i][j][ii] * acc[i][j][ii];
        s += __shfl_xor(s, 1);
        s += __shfl_xor(s, 2);
        s += __shfl_xor(s, 4);
        s += __shfl_xor(s, 8);
        float sc = gam / sqrtf(s);
#pragma unroll
        for (int j = 0; j < 4; ++j) acc[i][j][ii] *= sc;
      }
  }
#pragma unroll
  for (int i = 0; i < 4; ++i)
#pragma unroll
    for (int j = 0; j < 4; ++j)
#pragma unroll
      for (int ii = 0; ii < 4; ++ii) {
        long row = crow0 + i * 16 + ii;
        int col = ccol0 + j * 16;
        if constexpr (sizeof(CT) == 2)
          C[row * NN + col] = f2b(acc[i][j][ii]);
        else
          C[row * NN + col] = acc[i][j][ii];
      }
}

// y-inner + XCD-chunked bijective swizzle; NWG must be a multiple of 32.
DEVFN void swz_xy(int bid, int nwg, int& bx, int& by) {
  int s = (bid & 7) * (nwg >> 3) + (bid >> 3);
  bx = s >> 2;
  by = s & 3;
}

__global__ __launch_bounds__(256, 3)
void proj_qkv(const float* __restrict__ Aq, const float* __restrict__ Ak,
              const float* __restrict__ Av, const unsigned short* __restrict__ Bq,
              const unsigned short* __restrict__ Bk, const unsigned short* __restrict__ Bv,
              const float* __restrict__ bq, const float* __restrict__ bk,
              const float* __restrict__ bv, unsigned short* __restrict__ Cq,
              unsigned short* __restrict__ Ck, unsigned short* __restrict__ Cv,
              const float* __restrict__ gamma) {
  const int z = blockIdx.z;
  const float* A = z == 0 ? Aq : (z == 1 ? Ak : Av);
  const unsigned short* B = z == 0 ? Bq : (z == 1 ? Bk : Bv);
  const float* bias = z == 0 ? bq : (z == 1 ? bk : bv);
  unsigned short* C = z == 0 ? Cq : (z == 1 ? Ck : Cv);
  int bx, by;
  swz_xy(blockIdx.x, 1024, bx, by);
  gemm_core<true, unsigned short>(A, B, bias, C, z == 0, gamma, bx, by);
}

__global__ __launch_bounds__(256, 3)
void gemm_final(const unsigned short* __restrict__ q, const unsigned short* __restrict__ Mt,
                const float* __restrict__ bo, float* __restrict__ out) {
  const int zb = blockIdx.z;
  int bx, by;
  swz_xy(blockIdx.x, 128, bx, by);
  gemm_core<false, float>(q + (long)zb * 2097152, Mt + (long)zb * 262144, bo,
                          out + (long)zb * 2097152, false, nullptr, bx, by);
}

// ---------------------------------------------------------------------------
// kv partials: part[chunk][bh][dk][dv] = sum over 256 n of k outer v
// ---------------------------------------------------------------------------
#define NCHUNK 16
__global__ __launch_bounds__(256, 2)
void kv_partial(const unsigned short* __restrict__ kq,
                const unsigned short* __restrict__ vq,
                float* __restrict__ part) {
  const int tid = threadIdx.x;
  const int chunk = blockIdx.x;
  const int bh = blockIdx.y;
  const int b = bh >> 3, h = bh & 7;
  __shared__ float ks[32][64];
  __shared__ float vs[32][64];
  const int dk0 = (tid & 15) * 4;
  const int dv0 = (tid >> 4) * 4;
  float acc[4][4] = {};
  const long nbase = (long)b * 4096 + chunk * 256;

  for (int sub = 0; sub < 8; ++sub) {
    long n0 = nbase + sub * 32;
#pragma unroll
    for (int i = 0; i < 2; ++i) {
      int e = i * 256 + tid;
      int row = e >> 4, c4 = e & 15;
      long gofs = (n0 + row) * 512 + h * 64 + c4 * 4;
      u16x4 kk = *reinterpret_cast<const u16x4*>(kq + gofs);
      u16x4 vv = *reinterpret_cast<const u16x4*>(vq + gofs);
      f32x4 kf = {b2f(kk[0]), b2f(kk[1]), b2f(kk[2]), b2f(kk[3])};
      f32x4 vf = {b2f(vv[0]), b2f(vv[1]), b2f(vv[2]), b2f(vv[3])};
      *reinterpret_cast<f32x4*>(&ks[row][c4 * 4]) = kf;
      *reinterpret_cast<f32x4*>(&vs[row][c4 * 4]) = vf;
    }
    __syncthreads();
#pragma unroll 4
    for (int n = 0; n < 32; ++n) {
      f32x4 kk = *reinterpret_cast<const f32x4*>(&ks[n][dk0]);
      f32x4 vv = *reinterpret_cast<const f32x4*>(&vs[n][dv0]);
#pragma unroll
      for (int a = 0; a < 4; ++a)
#pragma unroll
        for (int c = 0; c < 4; ++c)
          acc[a][c] += kk[a] * vv[c];
    }
    __syncthreads();
  }
  float* pg = part + ((long)chunk * 64 + bh) * 4096;
#pragma unroll
  for (int a = 0; a < 4; ++a) {
    f32x4 o = {acc[a][0], acc[a][1], acc[a][2], acc[a][3]};
    *reinterpret_cast<f32x4*>(pg + (dk0 + a) * 64 + dv0) = o;
  }
}

// reduce partials + L2-norm rows (over dv) * gamma -> kvn bf16 [bh][64][64]
__global__ __launch_bounds__(256)
void kv_normN(const float* __restrict__ part, const float* __restrict__ gamma,
              unsigned short* __restrict__ kvn) {
  const int bh = blockIdx.x, h = bh & 7;
  const int tid = threadIdx.x;
  __shared__ float kvs[4096];
  __shared__ float scale[64];
#pragma unroll
  for (int i = 0; i < 4; ++i) {
    int e4 = i * 256 + tid;
    const float* p = part + (long)bh * 4096 + e4 * 4;
    f32x4 s = {0.f, 0.f, 0.f, 0.f};
#pragma unroll
    for (int c = 0; c < NCHUNK; ++c) {
      f32x4 v = *reinterpret_cast<const f32x4*>(p + (long)c * 64 * 4096);
      s += v;
    }
    *reinterpret_cast<f32x4*>(kvs + e4 * 4) = s;
  }
  __syncthreads();
  if (tid < 64) {
    float s = 0.f;
    for (int dv = 0; dv < 64; ++dv) { float x = kvs[tid * 64 + dv]; s += x * x; }
    scale[tid] = gamma[h] / sqrtf(s);
  }
  __syncthreads();
#pragma unroll
  for (int i = 0; i < 4; ++i) {
    int e4 = i * 256 + tid;
    float sc = scale[e4 >> 4];
    f32x4 v = *reinterpret_cast<const f32x4*>(kvs + e4 * 4);
    u16x4 o = {f2b(v[0] * sc), f2b(v[1] * sc), f2b(v[2] * sc), f2b(v[3] * sc)};
    *reinterpret_cast<u16x4*>(kvn + (long)bh * 4096 + e4 * 4) = o;
  }
}

// Mt[b][c][h*64+dk] = sum_dv Wo[c][h*64+dv] * kvn[b,h][dk][dv]
__global__ __launch_bounds__(64)
void mt_kernel(const unsigned short* __restrict__ Wo_b,
               const unsigned short* __restrict__ kvn,
               unsigned short* __restrict__ Mt) {
  const int bid = blockIdx.x;
  const int bh = bid >> 2, seg = bid & 3;
  const int b = bh >> 3, h = bh & 7;
  const int lane = threadIdx.x;
  const int r = lane & 15, g = lane >> 4;
  f32x4 acc[8][4] = {};
  s16x8 bf[2][4];
#pragma unroll
  for (int ks = 0; ks < 2; ++ks)
#pragma unroll
    for (int j = 0; j < 4; ++j)
      bf[ks][j] = *reinterpret_cast<const s16x8*>(
          kvn + (long)bh * 4096 + (j * 16 + r) * 64 + ks * 32 + g * 8);
#pragma unroll
  for (int ks = 0; ks < 2; ++ks)
#pragma unroll
    for (int i = 0; i < 8; ++i) {
      s16x8 af = *reinterpret_cast<const s16x8*>(
          Wo_b + (long)(seg * 128 + i * 16 + r) * 512 + h * 64 + ks * 32 + g * 8);
#pragma unroll
      for (int j = 0; j < 4; ++j)
        acc[i][j] = __builtin_amdgcn_mfma_f32_16x16x32_bf16(af, bf[ks][j], acc[i][j], 0, 0, 0);
    }
#pragma unroll
  for (int i = 0; i < 8; ++i)
#pragma unroll
    for (int j = 0; j < 4; ++j)
#pragma unroll
      for (int ii = 0; ii < 4; ++ii) {
        int c = seg * 128 + i * 16 + g * 4 + ii;
        int dk = j * 16 + r;
        Mt[(long)b * 262144 + (long)c * 512 + h * 64 + dk] = f2b(acc[i][j][ii]);
      }
}

__global__ void cast4(const float* __restrict__ a0, const float* __restrict__ a1,
                      const float* __restrict__ a2, const float* __restrict__ a3,
                      unsigned short* __restrict__ o0, unsigned short* __restrict__ o1,
                      unsigned short* __restrict__ o2, unsigned short* __restrict__ o3) {
  const int y = blockIdx.y;
  const float* in = y == 0 ? a0 : (y == 1 ? a1 : (y == 2 ? a2 : a3));
  unsigned short* out = y == 0 ? o0 : (y == 1 ? o1 : (y == 2 ? o2 : o3));
  int i = blockIdx.x * 256 + threadIdx.x;
  f32x4 v = reinterpret_cast<const f32x4*>(in)[i];
  reinterpret_cast<u16x4*>(out)[i] = u16x4{f2b(v[0]), f2b(v[1]), f2b(v[2]), f2b(v[3])};
}

// ---------------------------------------------------------------------------
extern "C" void kernel_launch(void* const* d_in, const int* in_sizes, int n_in,
                              void* d_out, int out_size, void* d_ws, size_t ws_size,
                              hipStream_t stream) {
  const float* queries = (const float*)d_in[0];
  const float* keys    = (const float*)d_in[1];
  const float* values  = (const float*)d_in[2];
  const float* Wq = (const float*)d_in[3];
  const float* bq = (const float*)d_in[4];
  const float* Wk = (const float*)d_in[5];
  const float* bk = (const float*)d_in[6];
  const float* Wv = (const float*)d_in[7];
  const float* bv = (const float*)d_in[8];
  const float* Wo = (const float*)d_in[9];
  const float* bo = (const float*)d_in[10];
  const float* gamma = (const float*)d_in[11];

  unsigned short* Wq_b = (unsigned short*)d_ws;            // 512 KB each
  unsigned short* Wk_b = Wq_b + 262144;
  unsigned short* Wv_b = Wk_b + 262144;
  unsigned short* Wo_b = Wv_b + 262144;
  unsigned short* q_b  = Wo_b + 262144;                    // 32 MB (holds q_n)
  unsigned short* kvn  = q_b + 16777216;                   // 512 KB
  float* part = (float*)(kvn + 262144);                    // 16 MB
  unsigned short* Mt = (unsigned short*)part;              // 4 MB (part dead by then)
  unsigned short* k_b = (unsigned short*)d_out;            // d_out scratch
  unsigned short* v_b = k_b + 16777216;
  float* out = (float*)d_out;

  cast4<<<dim3(256, 4), 256, 0, stream>>>(Wq, Wk, Wv, Wo, Wq_b, Wk_b, Wv_b, Wo_b);

  proj_qkv<<<dim3(1024, 1, 3), 256, 0, stream>>>(
      queries, keys, values, Wq_b, Wk_b, Wv_b, bq, bk, bv, q_b, k_b, v_b, gamma);

  kv_partial<<<dim3(NCHUNK, 64), 256, 0, stream>>>(k_b, v_b, part);
  kv_normN<<<64, 256, 0, stream>>>(part, gamma, kvn);
  mt_kernel<<<256, 64, 0, stream>>>(Wo_b, kvn, Mt);

  gemm_final<<<dim3(128, 1, 8), 256, 0, stream>>>(q_b, Mt, bo, out);
}

// Round 6
// 178.524 us; speedup vs baseline: 1.1438x; 1.1438x over previous
//
#include <hip/hip_runtime.h>

// UFO linear attention, MI355X (gfx950). B=8, N=4096, C=512, H=8, DK=DV=64.
//
// R9: 256x256-tile 8-phase GEMM core (HK/m201 schedule, plain HIP).
// R3-R8 showed the 128^2 2-barrier structure pins proj at ~410 TF (16%
// MfmaUtil) regardless of occupancy/staging variant. This port: BK=64,
// 8 waves (512 thr, 2Mx4N), LDS 128 KiB = 2buf x 2half x 128x128B per
// operand, per-phase {ds_read frags | stage 1 half-tile | 16 MFMA},
// counted vmcnt(4) at phases 4/8 only, raw barriers + sched_barrier(0)
// pinning, setprio(1) around MFMA. A-fp32 (proj): reg-load 2 phases
// early -> pk2 -> swizzled ds_write (lgkm-drained before phase-end bar).
// B and bf16-A: global_load_lds with pre-swizzled per-lane source.

typedef __attribute__((ext_vector_type(4))) float f32x4;
typedef __attribute__((ext_vector_type(8))) short s16x8;
typedef __attribute__((ext_vector_type(4))) unsigned short u16x4;
typedef __attribute__((ext_vector_type(4))) unsigned u32x4;

#define DEVFN __device__ __forceinline__

DEVFN unsigned short f2b(float f) {  // fp32 -> bf16 RNE
  union { float f; unsigned u; } un; un.f = f;
  unsigned r = un.u + 0x7fffu + ((un.u >> 16) & 1u);
  return (unsigned short)(r >> 16);
}
DEVFN float b2f(unsigned short us) {
  union { unsigned u; float f; } un; un.u = ((unsigned)us) << 16;
  return un.f;
}
// pack two fp32 -> dword of 2 bf16 (round-half-up): 2 adds + 1 v_perm
DEVFN unsigned pk2(float x0, float x1) {
  union { float f; unsigned u; } a, b;
  a.f = x0; b.f = x1;
  return __builtin_amdgcn_perm(b.u + 0x8000u, a.u + 0x8000u, 0x07060302u);
}
// async global->LDS, 16 B per lane; lds dest = wave-uniform base + lane*16
DEVFN void gl_lds16(const void* g, void* l) {
  __builtin_amdgcn_global_load_lds(
      (const __attribute__((address_space(1))) unsigned*)g,
      (__attribute__((address_space(3))) unsigned*)l, 16, 0, 0);
}

// ---------------------------------------------------------------------------
// 256x256 tile, BK=64, K=512 (8 K-tiles, 4 iterations of 8 phases).
// C[m][n] = sum_k A[m][k]*Bt[n][k] + bias[n]; optional fused head-norm.
// ---------------------------------------------------------------------------
template <bool AF32, typename CT>
DEVFN void gemm256(const void* Ain, const unsigned short* Bt,
                   const float* bias, CT* C, bool qnorm, const float* gamma,
                   int bx, int by) {
  constexpr int NN = 512;
  __shared__ __align__(16) char LA[65536];  // [2 buf][2 half][128][128B]
  __shared__ __align__(16) char LB[65536];
  const int tid = threadIdx.x, lane = tid & 63, wid = tid >> 6;
  const int r = lane & 15, g = lane >> 4;
  const int mw = wid >> 2;  // M-wave 0/1 -> A half
  const int nw = wid & 3;   // N-wave 0..3

  // fragment-read bases (swizzled slot ks*4+g XOR row&7 == r&7)
  const char* pa = LA + mw * 16384 + r * 128;
  const char* pb = LB + (nw >> 1) * 16384 + ((nw & 1) * 64 + r) * 128;
  const int sw0 = (g ^ (r & 7)) << 4;
  const int sw1 = ((4 + g) ^ (r & 7)) << 4;

  // B stage: pre-swizzled per-lane source, linear LDS dest (proven R5).
  const char* BsS = (const char*)Bt + (long)(by * 256 + (tid >> 3)) * 1024 +
                    ((tid & 7) ^ ((tid >> 3) & 7)) * 16;
  char* BdS = LB + wid * 1024;

  const char* AsS = nullptr;  // bf16 A gl_lds source (final)
  const char* AfS = nullptr;  // fp32 A reg source (proj)
  char* AdS = LA + wid * 1024;
  int aw0 = 0, aw1 = 0;       // swizzled ds_write offsets (proj)
  if constexpr (AF32) {
    AfS = (const char*)Ain + (long)(bx * 256 + (tid >> 2)) * 2048 +
          (tid & 3) * 64;
    const int rr = tid >> 2, s0 = (tid & 3) * 2;
    aw0 = rr * 128 + ((s0 ^ (rr & 7)) << 4);
    aw1 = rr * 128 + (((s0 + 1) ^ (rr & 7)) << 4);
  } else {
    AsS = (const char*)Ain + (long)(bx * 256 + (tid >> 3)) * 1024 +
          ((tid & 7) ^ ((tid >> 3) & 7)) * 16;
  }

  f32x4 acc[8][4] = {};
  s16x8 b0[4], b1[4];
  f32x4 rs0[4], rs1[4];  // proj A staging regs (h0 / h1 sets)

#define SB0 __builtin_amdgcn_sched_barrier(0);
#define BARR SB0 __builtin_amdgcn_s_barrier(); SB0
#define VMC(N) asm volatile("s_waitcnt vmcnt(" #N ")" ::: "memory");
#define LGK asm volatile("s_waitcnt lgkmcnt(0)" ::: "memory");

#define RA(dv, BUF, FOFF, SW)                                                  \
  _Pragma("unroll") for (int f = 0; f < 4; ++f)                                \
      dv[f] = *reinterpret_cast<const s16x8*>(pa + (BUF)*32768 + (FOFF) +      \
                                              f * 2048 + (SW));
#define RB(dv, BUF, SW)                                                        \
  _Pragma("unroll") for (int j = 0; j < 4; ++j)                                \
      dv[j] = *reinterpret_cast<const s16x8*>(pb + (BUF)*32768 + j * 2048 +    \
                                              (SW));
#define MM(av, bv, FB)                                                         \
  _Pragma("unroll") for (int f = 0; f < 4; ++f)                                \
      _Pragma("unroll") for (int j = 0; j < 4; ++j)                            \
      acc[(FB) + f][j] = __builtin_amdgcn_mfma_f32_16x16x32_bf16(              \
          av[f], bv[j], acc[(FB) + f][j], 0, 0, 0);

#define SGB(BUF, HALF, KT)                                                     \
  gl_lds16(BsS + ((HALF)*128) * 1024 + (KT)*128,                               \
           BdS + (BUF)*32768 + (HALF)*16384);                                  \
  gl_lds16(BsS + ((HALF)*128 + 64) * 1024 + (KT)*128,                          \
           BdS + (BUF)*32768 + (HALF)*16384 + 8192);
#define SGA(BUF, HALF, KT)                                                     \
  gl_lds16(AsS + ((HALF)*128) * 1024 + (KT)*128,                               \
           AdS + (BUF)*32768 + (HALF)*16384);                                  \
  gl_lds16(AsS + ((HALF)*128 + 64) * 1024 + (KT)*128,                          \
           AdS + (BUF)*32768 + (HALF)*16384 + 8192);
#define LDA(RS, HALF, KT)                                                      \
  _Pragma("unroll") for (int u = 0; u < 4; ++u)                                \
      RS[u] = *reinterpret_cast<const f32x4*>(AfS + (long)(HALF)*262144 +      \
                                              (KT)*256 + u * 16);
#define WRA(RS, BUF, HALF)                                                     \
  {                                                                            \
    unsigned w0 = pk2(RS[0][0], RS[0][1]), w1 = pk2(RS[0][2], RS[0][3]);       \
    unsigned w2 = pk2(RS[1][0], RS[1][1]), w3 = pk2(RS[1][2], RS[1][3]);       \
    unsigned w4 = pk2(RS[2][0], RS[2][1]), w5 = pk2(RS[2][2], RS[2][3]);       \
    unsigned w6 = pk2(RS[3][0], RS[3][1]), w7 = pk2(RS[3][2], RS[3][3]);       \
    *reinterpret_cast<u32x4*>(LA + (BUF)*32768 + (HALF)*16384 + aw0) =         \
        u32x4{w0, w1, w2, w3};                                                 \
    *reinterpret_cast<u32x4*>(LA + (BUF)*32768 + (HALF)*16384 + aw1) =         \
        u32x4{w4, w5, w6, w7};                                                 \
  }

  // ---- prologue: T0 (buf0) fully staged; T1.B (buf1); proj: T1.A loads ----
  if constexpr (AF32) {
    LDA(rs0, 0, 0) LDA(rs1, 1, 0)
    WRA(rs0, 0, 0) WRA(rs1, 0, 1)
    SGB(0, 0, 0) SGB(0, 1, 0) SGB(1, 0, 1) SGB(1, 1, 1)
    asm volatile("s_waitcnt vmcnt(0) lgkmcnt(0)" ::: "memory");
    SB0
    LDA(rs0, 0, 1) LDA(rs1, 1, 1)
  } else {
    SGA(0, 0, 0) SGA(0, 1, 0)
    SGB(0, 0, 0) SGB(0, 1, 0) SGB(1, 0, 1) SGB(1, 1, 1)
    VMC(0)
  }
  BARR

  // ---- 8-phase iteration: computes T[KT0] (buf0) then T[KT0+1] (buf1);
  //      stages T[KT0+1].A (P1,P2), T[KT0+2].B (P3,P4), T[KT0+2].A (P5,P6),
  //      T[KT0+3].B (P7,P8); proj A-loads issued 2 phases early. ----
#define ITER(KT0v, LASTv)                                                      \
  { /* P1 */                                                                   \
    s16x8 a[4];                                                                \
    RA(a, 0, 0, sw0) RB(b0, 0, sw0)                                            \
    if constexpr (AF32) { WRA(rs0, 1, 0) } else { SGA(1, 0, (KT0v) + 1) }      \
    BARR __builtin_amdgcn_s_setprio(1); MM(a, b0, 0)                           \
    __builtin_amdgcn_s_setprio(0);                                             \
    if constexpr (AF32) { LGK }                                                \
    BARR                                                                       \
  }                                                                            \
  { /* P2 */                                                                   \
    s16x8 a[4];                                                                \
    RA(a, 0, 0, sw1) RB(b1, 0, sw1)                                            \
    if constexpr (AF32) { WRA(rs1, 1, 1) } else { SGA(1, 1, (KT0v) + 1) }      \
    BARR __builtin_amdgcn_s_setprio(1); MM(a, b1, 0)                           \
    __builtin_amdgcn_s_setprio(0);                                             \
    if constexpr (AF32) { LGK }                                                \
    BARR                                                                       \
  }                                                                            \
  { /* P3 */                                                                   \
    s16x8 a[4];                                                                \
    RA(a, 0, 8192, sw0)                                                        \
    if (!(LASTv)) {                                                            \
      SGB(0, 0, (KT0v) + 2) SB0                                                \
      if constexpr (AF32) { LDA(rs0, 0, (KT0v) + 2) }                          \
    }                                                                          \
    BARR __builtin_amdgcn_s_setprio(1); MM(a, b0, 4)                           \
    __builtin_amdgcn_s_setprio(0); BARR                                        \
  }                                                                            \
  { /* P4 */                                                                   \
    s16x8 a[4];                                                                \
    RA(a, 0, 8192, sw1)                                                        \
    if (!(LASTv)) {                                                            \
      SGB(0, 1, (KT0v) + 2) SB0                                                \
      if constexpr (AF32) { LDA(rs1, 1, (KT0v) + 2) }                          \
      VMC(4)                                                                   \
    } else { VMC(0) }                                                          \
    BARR __builtin_amdgcn_s_setprio(1); MM(a, b1, 4)                           \
    __builtin_amdgcn_s_setprio(0); BARR                                        \
  }                                                                            \
  { /* P5 */                                                                   \
    s16x8 a[4];                                                                \
    RA(a, 1, 0, sw0) RB(b0, 1, sw0)                                            \
    if (!(LASTv)) {                                                            \
      if constexpr (AF32) { WRA(rs0, 0, 0) } else { SGA(0, 0, (KT0v) + 2) }    \
    }                                                                          \
    BARR __builtin_amdgcn_s_setprio(1); MM(a, b0, 0)                           \
    __builtin_amdgcn_s_setprio(0);                                             \
    if constexpr (AF32) { if (!(LASTv)) { LGK } }                              \
    BARR                                                                       \
  }                                                                            \
  { /* P6 */                                                                   \
    s16x8 a[4];                                                                \
    RA(a, 1, 0, sw1) RB(b1, 1, sw1)                                            \
    if (!(LASTv)) {                                                            \
      if constexpr (AF32) { WRA(rs1, 0, 1) } else { SGA(0, 1, (KT0v) + 2) }    \
    }                                                                          \
    BARR __builtin_amdgcn_s_setprio(1); MM(a, b1, 0)                           \
    __builtin_amdgcn_s_setprio(0);                                             \
    if constexpr (AF32) { if (!(LASTv)) { LGK } }                              \
    BARR                                                                       \
  }                                                                            \
  { /* P7 */                                                                   \
    s16x8 a[4];                                                                \
    RA(a, 1, 8192, sw0)                                                        \
    if (!(LASTv)) {                                                            \
      SGB(1, 0, (KT0v) + 3) SB0                                                \
      if constexpr (AF32) { LDA(rs0, 0, (KT0v) + 3) }                          \
    }                                                                          \
    BARR __builtin_amdgcn_s_setprio(1); MM(a, b0, 4)                           \
    __builtin_amdgcn_s_setprio(0); BARR                                        \
  }                                                                            \
  { /* P8 */                                                                   \
    s16x8 a[4];                                                                \
    RA(a, 1, 8192, sw1)                                                        \
    if (!(LASTv)) {                                                            \
      SGB(1, 1, (KT0v) + 3) SB0                                                \
      if constexpr (AF32) { LDA(rs1, 1, (KT0v) + 3) }                          \
      VMC(4)                                                                   \
    }                                                                          \
    BARR __builtin_amdgcn_s_setprio(1); MM(a, b1, 4)                           \
    __builtin_amdgcn_s_setprio(0); BARR                                        \
  }

  ITER(0, 0)
  ITER(2, 0)
  ITER(4, 0)
  ITER(6, 1)

#undef ITER
#undef RA
#undef RB
#undef MM
#undef SGB
#undef SGA
#undef LDA
#undef WRA
#undef SB0
#undef BARR
#undef VMC
#undef LGK

  // ---- epilogue (C/D layout: col=lane&15, row=(lane>>4)*4+ii) ----
  const int crow0 = bx * 256 + mw * 128 + g * 4;
  const int ccol0 = by * 256 + nw * 64 + r;
#pragma unroll
  for (int j = 0; j < 4; ++j) {
    float bv = bias[ccol0 + j * 16];
#pragma unroll
    for (int f = 0; f < 8; ++f)
#pragma unroll
      for (int ii = 0; ii < 4; ++ii) acc[f][j][ii] += bv;
  }
  if (qnorm) {  // wave's 64 cols == one head; L2-norm over them per row
    const float gam = gamma[by * 4 + nw];
#pragma unroll
    for (int f = 0; f < 8; ++f)
#pragma unroll
      for (int ii = 0; ii < 4; ++ii) {
        float s = 0.f;
#pragma unroll
        for (int j = 0; j < 4; ++j) s += acc[f][j][ii] * acc[f][j][ii];
        s += __shfl_xor(s, 1);
        s += __shfl_xor(s, 2);
        s += __shfl_xor(s, 4);
        s += __shfl_xor(s, 8);
        float sc = gam / sqrtf(s);
#pragma unroll
        for (int j = 0; j < 4; ++j) acc[f][j][ii] *= sc;
      }
  }
#pragma unroll
  for (int f = 0; f < 8; ++f)
#pragma unroll
    for (int j = 0; j < 4; ++j)
#pragma unroll
      for (int ii = 0; ii < 4; ++ii) {
        long row = crow0 + f * 16 + ii;
        int col = ccol0 + j * 16;
        if constexpr (sizeof(CT) == 2)
          C[row * NN + col] = f2b(acc[f][j][ii]);
        else
          C[row * NN + col] = acc[f][j][ii];
      }
}

__global__ __launch_bounds__(512, 1)
void proj_qkv(const float* __restrict__ Aq, const float* __restrict__ Ak,
              const float* __restrict__ Av, const unsigned short* __restrict__ Bq,
              const unsigned short* __restrict__ Bk, const unsigned short* __restrict__ Bv,
              const float* __restrict__ bq, const float* __restrict__ bk,
              const float* __restrict__ bv, unsigned short* __restrict__ Cq,
              unsigned short* __restrict__ Ck, unsigned short* __restrict__ Cv,
              const float* __restrict__ gamma) {
  const int z = blockIdx.y;
  const float* A = z == 0 ? Aq : (z == 1 ? Ak : Av);
  const unsigned short* B = z == 0 ? Bq : (z == 1 ? Bk : Bv);
  const float* bias = z == 0 ? bq : (z == 1 ? bk : bv);
  unsigned short* C = z == 0 ? Cq : (z == 1 ? Ck : Cv);
  // XCD-chunked bijective swizzle, nwg=256 (y-inner)
  const int bid = blockIdx.x;
  const int s = (bid & 7) * 32 + (bid >> 3);
  gemm256<true, unsigned short>(A, B, bias, C, z == 0, gamma, s >> 1, s & 1);
}

__global__ __launch_bounds__(512, 1)
void gemm_final(const unsigned short* __restrict__ q, const unsigned short* __restrict__ Mt,
                const float* __restrict__ bo, float* __restrict__ out) {
  const int zb = blockIdx.y;
  const int bid = blockIdx.x;  // nwg=32
  const int s = (bid & 7) * 4 + (bid >> 3);
  gemm256<false, float>(q + (long)zb * 2097152, Mt + (long)zb * 262144, bo,
                        out + (long)zb * 2097152, false, nullptr, s >> 1,
                        s & 1);
}

// ---------------------------------------------------------------------------
// kv partials: part[chunk][bh][dk][dv] = sum over 256 n of k outer v
// ---------------------------------------------------------------------------
#define NCHUNK 16
__global__ __launch_bounds__(256, 2)
void kv_partial(const unsigned short* __restrict__ kq,
                const unsigned short* __restrict__ vq,
                float* __restrict__ part) {
  const int tid = threadIdx.x;
  const int chunk = blockIdx.x;
  const int bh = blockIdx.y;
  const int b = bh >> 3, h = bh & 7;
  __shared__ float ks[32][64];
  __shared__ float vs[32][64];
  const int dk0 = (tid & 15) * 4;
  const int dv0 = (tid >> 4) * 4;
  float acc[4][4] = {};
  const long nbase = (long)b * 4096 + chunk * 256;

  for (int sub = 0; sub < 8; ++sub) {
    long n0 = nbase + sub * 32;
#pragma unroll
    for (int i = 0; i < 2; ++i) {
      int e = i * 256 + tid;
      int row = e >> 4, c4 = e & 15;
      long gofs = (n0 + row) * 512 + h * 64 + c4 * 4;
      u16x4 kk = *reinterpret_cast<const u16x4*>(kq + gofs);
      u16x4 vv = *reinterpret_cast<const u16x4*>(vq + gofs);
      f32x4 kf = {b2f(kk[0]), b2f(kk[1]), b2f(kk[2]), b2f(kk[3])};
      f32x4 vf = {b2f(vv[0]), b2f(vv[1]), b2f(vv[2]), b2f(vv[3])};
      *reinterpret_cast<f32x4*>(&ks[row][c4 * 4]) = kf;
      *reinterpret_cast<f32x4*>(&vs[row][c4 * 4]) = vf;
    }
    __syncthreads();
#pragma unroll 4
    for (int n = 0; n < 32; ++n) {
      f32x4 kk = *reinterpret_cast<const f32x4*>(&ks[n][dk0]);
      f32x4 vv = *reinterpret_cast<const f32x4*>(&vs[n][dv0]);
#pragma unroll
      for (int a = 0; a < 4; ++a)
#pragma unroll
        for (int c = 0; c < 4; ++c)
          acc[a][c] += kk[a] * vv[c];
    }
    __syncthreads();
  }
  float* pg = part + ((long)chunk * 64 + bh) * 4096;
#pragma unroll
  for (int a = 0; a < 4; ++a) {
    f32x4 o = {acc[a][0], acc[a][1], acc[a][2], acc[a][3]};
    *reinterpret_cast<f32x4*>(pg + (dk0 + a) * 64 + dv0) = o;
  }
}

// reduce partials + L2-norm rows (over dv) * gamma -> kvn bf16 [bh][64][64]
__global__ __launch_bounds__(256)
void kv_normN(const float* __restrict__ part, const float* __restrict__ gamma,
              unsigned short* __restrict__ kvn) {
  const int bh = blockIdx.x, h = bh & 7;
  const int tid = threadIdx.x;
  __shared__ float kvs[4096];
  __shared__ float scale[64];
#pragma unroll
  for (int i = 0; i < 4; ++i) {
    int e4 = i * 256 + tid;
    const float* p = part + (long)bh * 4096 + e4 * 4;
    f32x4 s = {0.f, 0.f, 0.f, 0.f};
#pragma unroll
    for (int c = 0; c < NCHUNK; ++c) {
      f32x4 v = *reinterpret_cast<const f32x4*>(p + (long)c * 64 * 4096);
      s += v;
    }
    *reinterpret_cast<f32x4*>(kvs + e4 * 4) = s;
  }
  __syncthreads();
  if (tid < 64) {
    float s = 0.f;
    for (int dv = 0; dv < 64; ++dv) { float x = kvs[tid * 64 + dv]; s += x * x; }
    scale[tid] = gamma[h] / sqrtf(s);
  }
  __syncthreads();
#pragma unroll
  for (int i = 0; i < 4; ++i) {
    int e4 = i * 256 + tid;
    float sc = scale[e4 >> 4];
    f32x4 v = *reinterpret_cast<const f32x4*>(kvs + e4 * 4);
    u16x4 o = {f2b(v[0] * sc), f2b(v[1] * sc), f2b(v[2] * sc), f2b(v[3] * sc)};
    *reinterpret_cast<u16x4*>(kvn + (long)bh * 4096 + e4 * 4) = o;
  }
}

// Mt[b][c][h*64+dk] = sum_dv Wo[c][h*64+dv] * kvn[b,h][dk][dv]
__global__ __launch_bounds__(64)
void mt_kernel(const unsigned short* __restrict__ Wo_b,
               const unsigned short* __restrict__ kvn,
               unsigned short* __restrict__ Mt) {
  const int bid = blockIdx.x;
  const int bh = bid >> 2, seg = bid & 3;
  const int b = bh >> 3, h = bh & 7;
  const int lane = threadIdx.x;
  const int r = lane & 15, g = lane >> 4;
  f32x4 acc[8][4] = {};
  s16x8 bf[2][4];
#pragma unroll
  for (int ks = 0; ks < 2; ++ks)
#pragma unroll
    for (int j = 0; j < 4; ++j)
      bf[ks][j] = *reinterpret_cast<const s16x8*>(
          kvn + (long)bh * 4096 + (j * 16 + r) * 64 + ks * 32 + g * 8);
#pragma unroll
  for (int ks = 0; ks < 2; ++ks)
#pragma unroll
    for (int i = 0; i < 8; ++i) {
      s16x8 af = *reinterpret_cast<const s16x8*>(
          Wo_b + (long)(seg * 128 + i * 16 + r) * 512 + h * 64 + ks * 32 + g * 8);
#pragma unroll
      for (int j = 0; j < 4; ++j)
        acc[i][j] = __builtin_amdgcn_mfma_f32_16x16x32_bf16(af, bf[ks][j], acc[i][j], 0, 0, 0);
    }
#pragma unroll
  for (int i = 0; i < 8; ++i)
#pragma unroll
    for (int j = 0; j < 4; ++j)
#pragma unroll
      for (int ii = 0; ii < 4; ++ii) {
        int c = seg * 128 + i * 16 + g * 4 + ii;
        int dk = j * 16 + r;
        Mt[(long)b * 262144 + (long)c * 512 + h * 64 + dk] = f2b(acc[i][j][ii]);
      }
}

__global__ void cast4(const float* __restrict__ a0, const float* __restrict__ a1,
                      const float* __restrict__ a2, const float* __restrict__ a3,
                      unsigned short* __restrict__ o0, unsigned short* __restrict__ o1,
                      unsigned short* __restrict__ o2, unsigned short* __restrict__ o3) {
  const int y = blockIdx.y;
  const float* in = y == 0 ? a0 : (y == 1 ? a1 : (y == 2 ? a2 : a3));
  unsigned short* out = y == 0 ? o0 : (y == 1 ? o1 : (y == 2 ? o2 : o3));
  int i = blockIdx.x * 256 + threadIdx.x;
  f32x4 v = reinterpret_cast<const f32x4*>(in)[i];
  reinterpret_cast<u16x4*>(out)[i] = u16x4{f2b(v[0]), f2b(v[1]), f2b(v[2]), f2b(v[3])};
}

// ---------------------------------------------------------------------------
extern "C" void kernel_launch(void* const* d_in, const int* in_sizes, int n_in,
                              void* d_out, int out_size, void* d_ws, size_t ws_size,
                              hipStream_t stream) {
  const float* queries = (const float*)d_in[0];
  const float* keys    = (const float*)d_in[1];
  const float* values  = (const float*)d_in[2];
  const float* Wq = (const float*)d_in[3];
  const float* bq = (const float*)d_in[4];
  const float* Wk = (const float*)d_in[5];
  const float* bk = (const float*)d_in[6];
  const float* Wv = (const float*)d_in[7];
  const float* bv = (const float*)d_in[8];
  const float* Wo = (const float*)d_in[9];
  const float* bo = (const float*)d_in[10];
  const float* gamma = (const float*)d_in[11];

  unsigned short* Wq_b = (unsigned short*)d_ws;            // 512 KB each
  unsigned short* Wk_b = Wq_b + 262144;
  unsigned short* Wv_b = Wk_b + 262144;
  unsigned short* Wo_b = Wv_b + 262144;
  unsigned short* q_b  = Wo_b + 262144;                    // 32 MB (holds q_n)
  unsigned short* kvn  = q_b + 16777216;                   // 512 KB
  float* part = (float*)(kvn + 262144);                    // 16 MB
  unsigned short* Mt = (unsigned short*)part;              // 4 MB (part dead by then)
  unsigned short* k_b = (unsigned short*)d_out;            // d_out scratch
  unsigned short* v_b = k_b + 16777216;
  float* out = (float*)d_out;

  cast4<<<dim3(256, 4), 256, 0, stream>>>(Wq, Wk, Wv, Wo, Wq_b, Wk_b, Wv_b, Wo_b);

  proj_qkv<<<dim3(256, 3), 512, 0, stream>>>(
      queries, keys, values, Wq_b, Wk_b, Wv_b, bq, bk, bv, q_b, k_b, v_b, gamma);

  kv_partial<<<dim3(NCHUNK, 64), 256, 0, stream>>>(k_b, v_b, part);
  kv_normN<<<64, 256, 0, stream>>>(part, gamma, kvn);
  mt_kernel<<<256, 64, 0, stream>>>(Wo_b, kvn, Mt);

  gemm_final<<<dim3(32, 8), 512, 0, stream>>>(q_b, Mt, bo, out);
}

// Round 7
// 176.493 us; speedup vs baseline: 1.1570x; 1.0115x over previous
//
#include <hip/hip_runtime.h>

// UFO linear attention, MI355X (gfx950). B=8, N=4096, C=512, H=8, DK=DV=64.
//
// R10: R9's 256x256 8-phase core, de-serialized. R9 measured 2670 cyc/phase
// vs ~1000 floor: 16 barriers/iter forced read->wait->MFMA serial, and
// proj's VMC(4) waited on same-phase loads. Now: phases merged into PAIRS
// with only the 4 provably-required barriers/iter (WAR edges of the double
// buffer); proj drops ALL manual waitcnts (WRA's register-consumption
// vmcnt waits drain older gl_lds in-order before any read); bf16 path
// keeps counted VMC(4) at pair-B/D ends; middle iters are a runtime loop
// (I$ shrink). Staging addresses/swizzles/epilogue identical to R9 (passed).

typedef __attribute__((ext_vector_type(4))) float f32x4;
typedef __attribute__((ext_vector_type(8))) short s16x8;
typedef __attribute__((ext_vector_type(4))) unsigned short u16x4;
typedef __attribute__((ext_vector_type(4))) unsigned u32x4;

#define DEVFN __device__ __forceinline__

DEVFN unsigned short f2b(float f) {  // fp32 -> bf16 RNE
  union { float f; unsigned u; } un; un.f = f;
  unsigned r = un.u + 0x7fffu + ((un.u >> 16) & 1u);
  return (unsigned short)(r >> 16);
}
DEVFN float b2f(unsigned short us) {
  union { unsigned u; float f; } un; un.u = ((unsigned)us) << 16;
  return un.f;
}
// pack two fp32 -> dword of 2 bf16 (round-half-up): 2 adds + 1 v_perm
DEVFN unsigned pk2(float x0, float x1) {
  union { float f; unsigned u; } a, b;
  a.f = x0; b.f = x1;
  return __builtin_amdgcn_perm(b.u + 0x8000u, a.u + 0x8000u, 0x07060302u);
}
// async global->LDS, 16 B per lane; lds dest = wave-uniform base + lane*16
DEVFN void gl_lds16(const void* g, void* l) {
  __builtin_amdgcn_global_load_lds(
      (const __attribute__((address_space(1))) unsigned*)g,
      (__attribute__((address_space(3))) unsigned*)l, 16, 0, 0);
}

// ---------------------------------------------------------------------------
// 256x256 tile, BK=64, K=512 (8 K-tiles; iter = 2 K-tiles = 4 pairs).
// C[m][n] = sum_k A[m][k]*Bt[n][k] + bias[n]; optional fused head-norm.
// ---------------------------------------------------------------------------
template <bool AF32, typename CT>
DEVFN void gemm256(const void* Ain, const unsigned short* Bt,
                   const float* bias, CT* C, bool qnorm, const float* gamma,
                   int bx, int by) {
  constexpr int NN = 512;
  __shared__ __align__(16) char LA[65536];  // [2 buf][2 half][128][128B]
  __shared__ __align__(16) char LB[65536];
  const int tid = threadIdx.x, lane = tid & 63, wid = tid >> 6;
  const int r = lane & 15, g = lane >> 4;
  const int mw = wid >> 2;  // M-wave 0/1 -> A half
  const int nw = wid & 3;   // N-wave 0..3

  const char* pa = LA + mw * 16384 + r * 128;
  const char* pb = LB + (nw >> 1) * 16384 + ((nw & 1) * 64 + r) * 128;
  const int sw0 = (g ^ (r & 7)) << 4;
  const int sw1 = ((4 + g) ^ (r & 7)) << 4;

  // B stage: pre-swizzled per-lane source, linear LDS dest (proven R5/R9).
  const char* BsS = (const char*)Bt + (long)(by * 256 + (tid >> 3)) * 1024 +
                    ((tid & 7) ^ ((tid >> 3) & 7)) * 16;
  char* BdS = LB + wid * 1024;

  const char* AsS = nullptr;  // bf16 A gl_lds source (final)
  const char* AfS = nullptr;  // fp32 A reg source (proj)
  char* AdS = LA + wid * 1024;
  int aw0 = 0, aw1 = 0;       // swizzled ds_write offsets (proj)
  if constexpr (AF32) {
    AfS = (const char*)Ain + (long)(bx * 256 + (tid >> 2)) * 2048 +
          (tid & 3) * 64;
    const int rr = tid >> 2, s0 = (tid & 3) * 2;
    aw0 = rr * 128 + ((s0 ^ (rr & 7)) << 4);
    aw1 = rr * 128 + (((s0 + 1) ^ (rr & 7)) << 4);
  } else {
    AsS = (const char*)Ain + (long)(bx * 256 + (tid >> 3)) * 1024 +
          ((tid & 7) ^ ((tid >> 3) & 7)) * 16;
  }

  f32x4 acc[8][4] = {};
  s16x8 b0[4], b1[4];
  f32x4 rs0[4], rs1[4];  // proj A staging regs (h0 / h1 sets)

#define SB0 __builtin_amdgcn_sched_barrier(0);
#define BARR SB0 __builtin_amdgcn_s_barrier(); SB0
#define VMC(N) asm volatile("s_waitcnt vmcnt(" #N ")" ::: "memory");
#define SETP1 __builtin_amdgcn_s_setprio(1);
#define SETP0 __builtin_amdgcn_s_setprio(0);

#define RA(dv, BUF, FOFF, SW)                                                  \
  _Pragma("unroll") for (int f = 0; f < 4; ++f)                                \
      dv[f] = *reinterpret_cast<const s16x8*>(pa + (BUF)*32768 + (FOFF) +      \
                                              f * 2048 + (SW));
#define RB(dv, BUF, SW)                                                        \
  _Pragma("unroll") for (int j = 0; j < 4; ++j)                                \
      dv[j] = *reinterpret_cast<const s16x8*>(pb + (BUF)*32768 + j * 2048 +    \
                                              (SW));
#define MM(av, bv, FB)                                                         \
  _Pragma("unroll") for (int f = 0; f < 4; ++f)                                \
      _Pragma("unroll") for (int j = 0; j < 4; ++j)                            \
      acc[(FB) + f][j] = __builtin_amdgcn_mfma_f32_16x16x32_bf16(              \
          av[f], bv[j], acc[(FB) + f][j], 0, 0, 0);

#define SGB(BUF, HALF, KT)                                                     \
  gl_lds16(BsS + ((HALF)*128) * 1024 + (KT)*128,                               \
           BdS + (BUF)*32768 + (HALF)*16384);                                  \
  gl_lds16(BsS + ((HALF)*128 + 64) * 1024 + (KT)*128,                          \
           BdS + (BUF)*32768 + (HALF)*16384 + 8192);
#define SGA(BUF, HALF, KT)                                                     \
  gl_lds16(AsS + ((HALF)*128) * 1024 + (KT)*128,                               \
           AdS + (BUF)*32768 + (HALF)*16384);                                  \
  gl_lds16(AsS + ((HALF)*128 + 64) * 1024 + (KT)*128,                          \
           AdS + (BUF)*32768 + (HALF)*16384 + 8192);
#define LDA(RS, HALF, KT)                                                      \
  _Pragma("unroll") for (int u = 0; u < 4; ++u)                                \
      RS[u] = *reinterpret_cast<const f32x4*>(AfS + (long)(HALF)*262144 +      \
                                              (KT)*256 + u * 16);
#define WRA(RS, BUF, HALF)                                                     \
  {                                                                            \
    unsigned w0 = pk2(RS[0][0], RS[0][1]), w1 = pk2(RS[0][2], RS[0][3]);       \
    unsigned w2 = pk2(RS[1][0], RS[1][1]), w3 = pk2(RS[1][2], RS[1][3]);       \
    unsigned w4 = pk2(RS[2][0], RS[2][1]), w5 = pk2(RS[2][2], RS[2][3]);       \
    unsigned w6 = pk2(RS[3][0], RS[3][1]), w7 = pk2(RS[3][2], RS[3][3]);       \
    *reinterpret_cast<u32x4*>(LA + (BUF)*32768 + (HALF)*16384 + aw0) =         \
        u32x4{w0, w1, w2, w3};                                                 \
    *reinterpret_cast<u32x4*>(LA + (BUF)*32768 + (HALF)*16384 + aw1) =         \
        u32x4{w4, w5, w6, w7};                                                 \
  }

  // ---- prologue: T0 (buf0) fully staged; T1.B (buf1); proj: T1.A loads ----
  if constexpr (AF32) {
    LDA(rs0, 0, 0) LDA(rs1, 1, 0)
    WRA(rs0, 0, 0) WRA(rs1, 0, 1)
    SGB(0, 0, 0) SGB(0, 1, 0) SGB(1, 0, 1) SGB(1, 1, 1)
    asm volatile("s_waitcnt vmcnt(0) lgkmcnt(0)" ::: "memory");
    SB0
    LDA(rs0, 0, 1) LDA(rs1, 1, 1)
  } else {
    SGA(0, 0, 0) SGA(0, 1, 0)
    SGB(0, 0, 0) SGB(0, 1, 0) SGB(1, 0, 1) SGB(1, 1, 1)
    VMC(0)
  }
  BARR

  // ---- iteration = 4 pairs; barriers ONLY at pair ends (WAR edges):
  //  A {rows 0-63 of T[kt0], K 0-63}: reads buf0.A/B; stage T[kt0+1].A->buf1
  //  B {rows 64-127}: reads buf0.A; stage T[kt0+2].B->buf0.B (+proj LDA)
  //  C {rows 0-63 of T[kt0+1]}: reads buf1.A/B; stage T[kt0+2].A->buf0.A
  //  D {rows 64-127}: reads buf1.A; stage T[kt0+3].B->buf1.B (+proj LDA)
#define ITERP(KT0v, LASTv)                                                     \
  { /* pair A */                                                               \
    s16x8 a0[4], a1[4];                                                        \
    RA(a0, 0, 0, sw0) RB(b0, 0, sw0)                                           \
    RA(a1, 0, 0, sw1) RB(b1, 0, sw1)                                           \
    if constexpr (AF32) { WRA(rs0, 1, 0) WRA(rs1, 1, 1) }                      \
    else { SGA(1, 0, (KT0v) + 1) SGA(1, 1, (KT0v) + 1) }                       \
    SETP1 MM(a0, b0, 0) MM(a1, b1, 0) SETP0                                    \
    BARR                                                                       \
  }                                                                            \
  { /* pair B */                                                               \
    s16x8 a0[4], a1[4];                                                        \
    RA(a0, 0, 8192, sw0) RA(a1, 0, 8192, sw1)                                  \
    if (!(LASTv)) {                                                            \
      SGB(0, 0, (KT0v) + 2) SGB(0, 1, (KT0v) + 2)                              \
      if constexpr (AF32) { LDA(rs0, 0, (KT0v) + 2) LDA(rs1, 1, (KT0v) + 2) }  \
    }                                                                          \
    SETP1 MM(a0, b0, 4) MM(a1, b1, 4) SETP0                                    \
    if constexpr (!AF32) { if (LASTv) { VMC(0) } else { VMC(4) } }             \
    BARR                                                                       \
  }                                                                            \
  { /* pair C */                                                               \
    s16x8 a0[4], a1[4];                                                        \
    RA(a0, 1, 0, sw0) RB(b0, 1, sw0)                                           \
    RA(a1, 1, 0, sw1) RB(b1, 1, sw1)                                           \
    if (!(LASTv)) {                                                            \
      if constexpr (AF32) { WRA(rs0, 0, 0) WRA(rs1, 0, 1) }                    \
      else { SGA(0, 0, (KT0v) + 2) SGA(0, 1, (KT0v) + 2) }                     \
    }                                                                          \
    SETP1 MM(a0, b0, 0) MM(a1, b1, 0) SETP0                                    \
    BARR                                                                       \
  }                                                                            \
  { /* pair D */                                                               \
    s16x8 a0[4], a1[4];                                                        \
    RA(a0, 1, 8192, sw0) RA(a1, 1, 8192, sw1)                                  \
    if (!(LASTv)) {                                                            \
      SGB(1, 0, (KT0v) + 3) SGB(1, 1, (KT0v) + 3)                              \
      if constexpr (AF32) { LDA(rs0, 0, (KT0v) + 3) LDA(rs1, 1, (KT0v) + 3) }  \
    }                                                                          \
    SETP1 MM(a0, b0, 4) MM(a1, b1, 4) SETP0                                    \
    if constexpr (!AF32) { if (!(LASTv)) { VMC(4) } }                          \
    BARR                                                                       \
  }

#pragma unroll 1
  for (int kt0 = 0; kt0 < 6; kt0 += 2) {
    ITERP(kt0, 0)
  }
  ITERP(6, 1)

#undef ITERP
#undef RA
#undef RB
#undef MM
#undef SGB
#undef SGA
#undef LDA
#undef WRA
#undef SB0
#undef BARR
#undef VMC
#undef SETP1
#undef SETP0

  // ---- epilogue (C/D layout: col=lane&15, row=(lane>>4)*4+ii) ----
  const int crow0 = bx * 256 + mw * 128 + g * 4;
  const int ccol0 = by * 256 + nw * 64 + r;
#pragma unroll
  for (int j = 0; j < 4; ++j) {
    float bv = bias[ccol0 + j * 16];
#pragma unroll
    for (int f = 0; f < 8; ++f)
#pragma unroll
      for (int ii = 0; ii < 4; ++ii) acc[f][j][ii] += bv;
  }
  if (qnorm) {  // wave's 64 cols == one head; L2-norm over them per row
    const float gam = gamma[by * 4 + nw];
#pragma unroll
    for (int f = 0; f < 8; ++f)
#pragma unroll
      for (int ii = 0; ii < 4; ++ii) {
        float s = 0.f;
#pragma unroll
        for (int j = 0; j < 4; ++j) s += acc[f][j][ii] * acc[f][j][ii];
        s += __shfl_xor(s, 1);
        s += __shfl_xor(s, 2);
        s += __shfl_xor(s, 4);
        s += __shfl_xor(s, 8);
        float sc = gam / sqrtf(s);
#pragma unroll
        for (int j = 0; j < 4; ++j) acc[f][j][ii] *= sc;
      }
  }
#pragma unroll
  for (int f = 0; f < 8; ++f)
#pragma unroll
    for (int j = 0; j < 4; ++j)
#pragma unroll
      for (int ii = 0; ii < 4; ++ii) {
        long row = crow0 + f * 16 + ii;
        int col = ccol0 + j * 16;
        if constexpr (sizeof(CT) == 2)
          C[row * NN + col] = f2b(acc[f][j][ii]);
        else
          C[row * NN + col] = acc[f][j][ii];
      }
}

__global__ __launch_bounds__(512, 1)
void proj_qkv(const float* __restrict__ Aq, const float* __restrict__ Ak,
              const float* __restrict__ Av, const unsigned short* __restrict__ Bq,
              const unsigned short* __restrict__ Bk, const unsigned short* __restrict__ Bv,
              const float* __restrict__ bq, const float* __restrict__ bk,
              const float* __restrict__ bv, unsigned short* __restrict__ Cq,
              unsigned short* __restrict__ Ck, unsigned short* __restrict__ Cv,
              const float* __restrict__ gamma) {
  const int z = blockIdx.y;
  const float* A = z == 0 ? Aq : (z == 1 ? Ak : Av);
  const unsigned short* B = z == 0 ? Bq : (z == 1 ? Bk : Bv);
  const float* bias = z == 0 ? bq : (z == 1 ? bk : bv);
  unsigned short* C = z == 0 ? Cq : (z == 1 ? Ck : Cv);
  // XCD-chunked bijective swizzle, nwg=256 (y-inner)
  const int bid = blockIdx.x;
  const int s = (bid & 7) * 32 + (bid >> 3);
  gemm256<true, unsigned short>(A, B, bias, C, z == 0, gamma, s >> 1, s & 1);
}

__global__ __launch_bounds__(512, 1)
void gemm_final(const unsigned short* __restrict__ q, const unsigned short* __restrict__ Mt,
                const float* __restrict__ bo, float* __restrict__ out) {
  const int zb = blockIdx.y;
  const int bid = blockIdx.x;  // nwg=32
  const int s = (bid & 7) * 4 + (bid >> 3);
  gemm256<false, float>(q + (long)zb * 2097152, Mt + (long)zb * 262144, bo,
                        out + (long)zb * 2097152, false, nullptr, s >> 1,
                        s & 1);
}

// ---------------------------------------------------------------------------
// kv partials: part[chunk][bh][dk][dv] = sum over 256 n of k outer v
// ---------------------------------------------------------------------------
#define NCHUNK 16
__global__ __launch_bounds__(256, 2)
void kv_partial(const unsigned short* __restrict__ kq,
                const unsigned short* __restrict__ vq,
                float* __restrict__ part) {
  const int tid = threadIdx.x;
  const int chunk = blockIdx.x;
  const int bh = blockIdx.y;
  const int b = bh >> 3, h = bh & 7;
  __shared__ float ks[32][64];
  __shared__ float vs[32][64];
  const int dk0 = (tid & 15) * 4;
  const int dv0 = (tid >> 4) * 4;
  float acc[4][4] = {};
  const long nbase = (long)b * 4096 + chunk * 256;

  for (int sub = 0; sub < 8; ++sub) {
    long n0 = nbase + sub * 32;
#pragma unroll
    for (int i = 0; i < 2; ++i) {
      int e = i * 256 + tid;
      int row = e >> 4, c4 = e & 15;
      long gofs = (n0 + row) * 512 + h * 64 + c4 * 4;
      u16x4 kk = *reinterpret_cast<const u16x4*>(kq + gofs);
      u16x4 vv = *reinterpret_cast<const u16x4*>(vq + gofs);
      f32x4 kf = {b2f(kk[0]), b2f(kk[1]), b2f(kk[2]), b2f(kk[3])};
      f32x4 vf = {b2f(vv[0]), b2f(vv[1]), b2f(vv[2]), b2f(vv[3])};
      *reinterpret_cast<f32x4*>(&ks[row][c4 * 4]) = kf;
      *reinterpret_cast<f32x4*>(&vs[row][c4 * 4]) = vf;
    }
    __syncthreads();
#pragma unroll 4
    for (int n = 0; n < 32; ++n) {
      f32x4 kk = *reinterpret_cast<const f32x4*>(&ks[n][dk0]);
      f32x4 vv = *reinterpret_cast<const f32x4*>(&vs[n][dv0]);
#pragma unroll
      for (int a = 0; a < 4; ++a)
#pragma unroll
        for (int c = 0; c < 4; ++c)
          acc[a][c] += kk[a] * vv[c];
    }
    __syncthreads();
  }
  float* pg = part + ((long)chunk * 64 + bh) * 4096;
#pragma unroll
  for (int a = 0; a < 4; ++a) {
    f32x4 o = {acc[a][0], acc[a][1], acc[a][2], acc[a][3]};
    *reinterpret_cast<f32x4*>(pg + (dk0 + a) * 64 + dv0) = o;
  }
}

// reduce partials + L2-norm rows (over dv) * gamma -> kvn bf16 [bh][64][64]
__global__ __launch_bounds__(256)
void kv_normN(const float* __restrict__ part, const float* __restrict__ gamma,
              unsigned short* __restrict__ kvn) {
  const int bh = blockIdx.x, h = bh & 7;
  const int tid = threadIdx.x;
  __shared__ float kvs[4096];
  __shared__ float scale[64];
#pragma unroll
  for (int i = 0; i < 4; ++i) {
    int e4 = i * 256 + tid;
    const float* p = part + (long)bh * 4096 + e4 * 4;
    f32x4 s = {0.f, 0.f, 0.f, 0.f};
#pragma unroll
    for (int c = 0; c < NCHUNK; ++c) {
      f32x4 v = *reinterpret_cast<const f32x4*>(p + (long)c * 64 * 4096);
      s += v;
    }
    *reinterpret_cast<f32x4*>(kvs + e4 * 4) = s;
  }
  __syncthreads();
  if (tid < 64) {
    float s = 0.f;
    for (int dv = 0; dv < 64; ++dv) { float x = kvs[tid * 64 + dv]; s += x * x; }
    scale[tid] = gamma[h] / sqrtf(s);
  }
  __syncthreads();
#pragma unroll
  for (int i = 0; i < 4; ++i) {
    int e4 = i * 256 + tid;
    float sc = scale[e4 >> 4];
    f32x4 v = *reinterpret_cast<const f32x4*>(kvs + e4 * 4);
    u16x4 o = {f2b(v[0] * sc), f2b(v[1] * sc), f2b(v[2] * sc), f2b(v[3] * sc)};
    *reinterpret_cast<u16x4*>(kvn + (long)bh * 4096 + e4 * 4) = o;
  }
}

// Mt[b][c][h*64+dk] = sum_dv Wo[c][h*64+dv] * kvn[b,h][dk][dv]
__global__ __launch_bounds__(64)
void mt_kernel(const unsigned short* __restrict__ Wo_b,
               const unsigned short* __restrict__ kvn,
               unsigned short* __restrict__ Mt) {
  const int bid = blockIdx.x;
  const int bh = bid >> 2, seg = bid & 3;
  const int b = bh >> 3, h = bh & 7;
  const int lane = threadIdx.x;
  const int r = lane & 15, g = lane >> 4;
  f32x4 acc[8][4] = {};
  s16x8 bf[2][4];
#pragma unroll
  for (int ks = 0; ks < 2; ++ks)
#pragma unroll
    for (int j = 0; j < 4; ++j)
      bf[ks][j] = *reinterpret_cast<const s16x8*>(
          kvn + (long)bh * 4096 + (j * 16 + r) * 64 + ks * 32 + g * 8);
#pragma unroll
  for (int ks = 0; ks < 2; ++ks)
#pragma unroll
    for (int i = 0; i < 8; ++i) {
      s16x8 af = *reinterpret_cast<const s16x8*>(
          Wo_b + (long)(seg * 128 + i * 16 + r) * 512 + h * 64 + ks * 32 + g * 8);
#pragma unroll
      for (int j = 0; j < 4; ++j)
        acc[i][j] = __builtin_amdgcn_mfma_f32_16x16x32_bf16(af, bf[ks][j], acc[i][j], 0, 0, 0);
    }
#pragma unroll
  for (int i = 0; i < 8; ++i)
#pragma unroll
    for (int j = 0; j < 4; ++j)
#pragma unroll
      for (int ii = 0; ii < 4; ++ii) {
        int c = seg * 128 + i * 16 + g * 4 + ii;
        int dk = j * 16 + r;
        Mt[(long)b * 262144 + (long)c * 512 + h * 64 + dk] = f2b(acc[i][j][ii]);
      }
}

__global__ void cast4(const float* __restrict__ a0, const float* __restrict__ a1,
                      const float* __restrict__ a2, const float* __restrict__ a3,
                      unsigned short* __restrict__ o0, unsigned short* __restrict__ o1,
                      unsigned short* __restrict__ o2, unsigned short* __restrict__ o3) {
  const int y = blockIdx.y;
  const float* in = y == 0 ? a0 : (y == 1 ? a1 : (y == 2 ? a2 : a3));
  unsigned short* out = y == 0 ? o0 : (y == 1 ? o1 : (y == 2 ? o2 : o3));
  int i = blockIdx.x * 256 + threadIdx.x;
  f32x4 v = reinterpret_cast<const f32x4*>(in)[i];
  reinterpret_cast<u16x4*>(out)[i] = u16x4{f2b(v[0]), f2b(v[1]), f2b(v[2]), f2b(v[3])};
}

// ---------------------------------------------------------------------------
extern "C" void kernel_launch(void* const* d_in, const int* in_sizes, int n_in,
                              void* d_out, int out_size, void* d_ws, size_t ws_size,
                              hipStream_t stream) {
  const float* queries = (const float*)d_in[0];
  const float* keys    = (const float*)d_in[1];
  const float* values  = (const float*)d_in[2];
  const float* Wq = (const float*)d_in[3];
  const float* bq = (const float*)d_in[4];
  const float* Wk = (const float*)d_in[5];
  const float* bk = (const float*)d_in[6];
  const float* Wv = (const float*)d_in[7];
  const float* bv = (const float*)d_in[8];
  const float* Wo = (const float*)d_in[9];
  const float* bo = (const float*)d_in[10];
  const float* gamma = (const float*)d_in[11];

  unsigned short* Wq_b = (unsigned short*)d_ws;            // 512 KB each
  unsigned short* Wk_b = Wq_b + 262144;
  unsigned short* Wv_b = Wk_b + 262144;
  unsigned short* Wo_b = Wv_b + 262144;
  unsigned short* q_b  = Wo_b + 262144;                    // 32 MB (holds q_n)
  unsigned short* kvn  = q_b + 16777216;                   // 512 KB
  float* part = (float*)(kvn + 262144);                    // 16 MB
  unsigned short* Mt = (unsigned short*)part;              // 4 MB (part dead by then)
  unsigned short* k_b = (unsigned short*)d_out;            // d_out scratch
  unsigned short* v_b = k_b + 16777216;
  float* out = (float*)d_out;

  cast4<<<dim3(256, 4), 256, 0, stream>>>(Wq, Wk, Wv, Wo, Wq_b, Wk_b, Wv_b, Wo_b);

  proj_qkv<<<dim3(256, 3), 512, 0, stream>>>(
      queries, keys, values, Wq_b, Wk_b, Wv_b, bq, bk, bv, q_b, k_b, v_b, gamma);

  kv_partial<<<dim3(NCHUNK, 64), 256, 0, stream>>>(k_b, v_b, part);
  kv_normN<<<64, 256, 0, stream>>>(part, gamma, kvn);
  mt_kernel<<<256, 64, 0, stream>>>(Wo_b, kvn, Mt);

  gemm_final<<<dim3(32, 8), 512, 0, stream>>>(q_b, Mt, bo, out);
}

// Round 8
// 174.551 us; speedup vs baseline: 1.1699x; 1.0111x over previous
//
#include <hip/hip_runtime.h>

// UFO linear attention, MI355X (gfx950). B=8, N=4096, C=512, H=8, DK=DV=64.
//
// R11: traffic-bound fix. R3-R10 pinned MfmaUtil at 14-17% across every
// schedule/occupancy/staging variant -> bottleneck is operand traffic:
// by-split read fp32 A twice (384 MB beyond-L2/dispatch, LLC-streamed).
// Now: full-N tiles (M128 x N512), A read ONCE, B (512KB/z) L2-resident.
// BK=32, LDS 80 KB (A 2x8K + B 2x32K), 1024-thread block = 16 waves ->
// 4 waves/SIMD residency (2x R9/10). Wave-tile 64x64 (acc 64 VGPR).
// One __syncthreads per K-tile, stage-ahead dbuf (R8's proven geometry:
// pk2 pack, 64-B-row XOR swizzle, pre-swizzled gl_lds source).

typedef __attribute__((ext_vector_type(4))) float f32x4;
typedef __attribute__((ext_vector_type(8))) short s16x8;
typedef __attribute__((ext_vector_type(4))) unsigned short u16x4;
typedef __attribute__((ext_vector_type(2))) unsigned u32x2;

#define DEVFN __device__ __forceinline__

DEVFN unsigned short f2b(float f) {  // fp32 -> bf16 RNE
  union { float f; unsigned u; } un; un.f = f;
  unsigned r = un.u + 0x7fffu + ((un.u >> 16) & 1u);
  return (unsigned short)(r >> 16);
}
DEVFN float b2f(unsigned short us) {
  union { unsigned u; float f; } un; un.u = ((unsigned)us) << 16;
  return un.f;
}
// pack two fp32 -> dword of 2 bf16 (round-half-up): 2 adds + 1 v_perm
DEVFN unsigned pk2(float x0, float x1) {
  union { float f; unsigned u; } a, b;
  a.f = x0; b.f = x1;
  return __builtin_amdgcn_perm(b.u + 0x8000u, a.u + 0x8000u, 0x07060302u);
}
// async global->LDS, 16 B per lane; lds dest = wave-uniform base + lane*16
DEVFN void gl_lds16(const void* g, void* l) {
  __builtin_amdgcn_global_load_lds(
      (const __attribute__((address_space(1))) unsigned*)g,
      (__attribute__((address_space(3))) unsigned*)l, 16, 0, 0);
}

// ---------------------------------------------------------------------------
// M-tile 128 x FULL N=512, BK=32, K=512 (16 K-tiles). 1024 thr = 16 waves,
// wave-tile 64x64 (mw = wid>>3 in 0..1, nw = wid&7 in 0..7).
// C[m][n] = sum_k A[m][k]*Bt[n][k] + bias[n]; optional fused head-norm
// (wave's 64 cols == one head == nw).
// ---------------------------------------------------------------------------
template <bool AF32, typename CT>
DEVFN void gemmN512(const void* Ain, const unsigned short* Bt,
                    const float* bias, CT* C, bool qnorm,
                    const float* gamma, int bx) {
  __shared__ __align__(16) char LA[2][8192];   // [buf][128 rows][64 B]
  __shared__ __align__(16) char LB[2][32768];  // [buf][512 rows][64 B]
  const int tid = threadIdx.x, lane = tid & 63, wid = tid >> 6;  // 0..15
  const int r = lane & 15, g = lane >> 4;
  const int mw = wid >> 3;  // 0..1  (M half)
  const int nw = wid & 7;   // 0..7  (N eighth = head)

  // B stage: 2 chunks/wave; chunk covers 16 rows; lane l -> row +(l>>2),
  // content-slot (l&3) taken from pre-swizzled source slot (l&3)^((l>>3)&3).
  const char* BsS = (const char*)Bt + (long)(wid * 32 + (lane >> 2)) * 1024 +
                    (((lane & 3) ^ ((lane >> 3) & 3)) * 16);

  // A sources
  const char* AfS = nullptr;  // fp32 (proj): thread t -> row t>>3, piece t&7
  const char* AsS = nullptr;  // bf16 (final): waves 0..7 stage 1 chunk each
  int awr = 0;                // swizzled 8-B ds_write offset (proj)
  if constexpr (AF32) {
    AfS = (const char*)Ain + (long)(bx * 128 + (tid >> 3)) * 2048 +
          (tid & 7) * 16;
    const int row = tid >> 3, p = tid & 7;
    awr = row * 64 + (((p >> 1) ^ ((row >> 1) & 3)) << 4) + (p & 1) * 8;
  } else {
    AsS = (const char*)Ain + (long)(bx * 128 + wid * 16 + (lane >> 2)) * 1024 +
          (((lane & 3) ^ ((lane >> 3) & 3)) * 16);
  }

  f32x4 acc[4][4] = {};
  f32x4 pa;  // proj fp32 A staging (1 per thread)

#define SGB(BUF, KT)                                                           \
  gl_lds16(BsS + (KT)*64, LB[BUF] + wid * 2048);                               \
  gl_lds16(BsS + 16384 + (KT)*64, LB[BUF] + wid * 2048 + 1024);
#define SGA(BUF, KT)                                                           \
  if (wid < 8) { gl_lds16(AsS + (KT)*64, LA[BUF] + wid * 1024); }
#define LDA(KT) pa = *reinterpret_cast<const f32x4*>(AfS + (KT)*128);
#define WRA(BUF)                                                               \
  {                                                                            \
    u32x2 w;                                                                   \
    w[0] = pk2(pa[0], pa[1]);                                                  \
    w[1] = pk2(pa[2], pa[3]);                                                  \
    *reinterpret_cast<u32x2*>(LA[BUF] + awr) = w;                              \
  }
#define COMPUTE(BUF)                                                           \
  {                                                                            \
    s16x8 a[4], b[4];                                                          \
    _Pragma("unroll") for (int i = 0; i < 4; ++i) {                            \
      int ar = mw * 64 + i * 16 + r;                                           \
      a[i] = *reinterpret_cast<const s16x8*>(                                  \
          LA[BUF] + ar * 64 + ((g ^ ((ar >> 1) & 3)) << 4));                   \
    }                                                                          \
    _Pragma("unroll") for (int j = 0; j < 4; ++j) {                            \
      int br = nw * 64 + j * 16 + r;                                           \
      b[j] = *reinterpret_cast<const s16x8*>(                                  \
          LB[BUF] + br * 64 + ((g ^ ((br >> 1) & 3)) << 4));                   \
    }                                                                          \
    _Pragma("unroll") for (int i = 0; i < 4; ++i)                              \
        _Pragma("unroll") for (int j = 0; j < 4; ++j) acc[i][j] =              \
        __builtin_amdgcn_mfma_f32_16x16x32_bf16(a[i], b[j], acc[i][j], 0, 0,   \
                                                0);                            \
  }

  // prologue: tile 0 -> buf 0
  if constexpr (AF32) {
    LDA(0) WRA(0)
  } else {
    SGA(0, 0)
  }
  SGB(0, 0)
  __syncthreads();

#pragma unroll 1
  for (int t = 0; t < 15; ++t) {
    const int cur = t & 1, nxt = cur ^ 1;
    if constexpr (AF32) { LDA(t + 1) }  // loads fly under COMPUTE
    SGB(nxt, t + 1)
    if constexpr (!AF32) { SGA(nxt, t + 1) }
    COMPUTE(cur)
    if constexpr (AF32) { WRA(nxt) }  // reg-dep wait lands after compute
    __syncthreads();
  }
  COMPUTE(1)

#undef SGB
#undef SGA
#undef LDA
#undef WRA
#undef COMPUTE

  // ---- epilogue (C/D layout: col=lane&15, row=(lane>>4)*4+ii) ----
  const int crow0 = bx * 128 + mw * 64 + g * 4;
  const int ccol0 = nw * 64 + r;
#pragma unroll
  for (int j = 0; j < 4; ++j) {
    float bv = bias[ccol0 + j * 16];
#pragma unroll
    for (int i = 0; i < 4; ++i)
#pragma unroll
      for (int ii = 0; ii < 4; ++ii) acc[i][j][ii] += bv;
  }
  if (qnorm) {  // wave's 64 cols == head nw; L2-norm over them per row
    const float gam = gamma[nw];
#pragma unroll
    for (int i = 0; i < 4; ++i)
#pragma unroll
      for (int ii = 0; ii < 4; ++ii) {
        float s = 0.f;
#pragma unroll
        for (int j = 0; j < 4; ++j) s += acc[i][j][ii] * acc[i][j][ii];
        s += __shfl_xor(s, 1);
        s += __shfl_xor(s, 2);
        s += __shfl_xor(s, 4);
        s += __shfl_xor(s, 8);
        float sc = gam / sqrtf(s);
#pragma unroll
        for (int j = 0; j < 4; ++j) acc[i][j][ii] *= sc;
      }
  }
#pragma unroll
  for (int i = 0; i < 4; ++i)
#pragma unroll
    for (int j = 0; j < 4; ++j)
#pragma unroll
      for (int ii = 0; ii < 4; ++ii) {
        long row = crow0 + i * 16 + ii;
        int col = ccol0 + j * 16;
        if constexpr (sizeof(CT) == 2)
          C[row * 512 + col] = f2b(acc[i][j][ii]);
        else
          C[row * 512 + col] = acc[i][j][ii];
      }
}

__global__ __launch_bounds__(1024)
void proj_qkv(const float* __restrict__ Aq, const float* __restrict__ Ak,
              const float* __restrict__ Av, const unsigned short* __restrict__ Bq,
              const unsigned short* __restrict__ Bk, const unsigned short* __restrict__ Bv,
              const float* __restrict__ bq, const float* __restrict__ bk,
              const float* __restrict__ bv, unsigned short* __restrict__ Cq,
              unsigned short* __restrict__ Ck, unsigned short* __restrict__ Cv,
              const float* __restrict__ gamma) {
  const int z = blockIdx.y;
  const float* A = z == 0 ? Aq : (z == 1 ? Ak : Av);
  const unsigned short* B = z == 0 ? Bq : (z == 1 ? Bk : Bv);
  const float* bias = z == 0 ? bq : (z == 1 ? bk : bv);
  unsigned short* C = z == 0 ? Cq : (z == 1 ? Ck : Cv);
  gemmN512<true, unsigned short>(A, B, bias, C, z == 0, gamma, blockIdx.x);
}

__global__ __launch_bounds__(1024)
void gemm_final(const unsigned short* __restrict__ q, const unsigned short* __restrict__ Mt,
                const float* __restrict__ bo, float* __restrict__ out) {
  const int zb = blockIdx.y;
  gemmN512<false, float>(q + (long)zb * 2097152, Mt + (long)zb * 262144, bo,
                         out + (long)zb * 2097152, false, nullptr, blockIdx.x);
}

// ---------------------------------------------------------------------------
// kv partials: part[chunk][bh][dk][dv] = sum over 256 n of k outer v
// ---------------------------------------------------------------------------
#define NCHUNK 16
__global__ __launch_bounds__(256, 2)
void kv_partial(const unsigned short* __restrict__ kq,
                const unsigned short* __restrict__ vq,
                float* __restrict__ part) {
  const int tid = threadIdx.x;
  const int chunk = blockIdx.x;
  const int bh = blockIdx.y;
  const int b = bh >> 3, h = bh & 7;
  __shared__ float ks[32][64];
  __shared__ float vs[32][64];
  const int dk0 = (tid & 15) * 4;
  const int dv0 = (tid >> 4) * 4;
  float acc[4][4] = {};
  const long nbase = (long)b * 4096 + chunk * 256;

  for (int sub = 0; sub < 8; ++sub) {
    long n0 = nbase + sub * 32;
#pragma unroll
    for (int i = 0; i < 2; ++i) {
      int e = i * 256 + tid;
      int row = e >> 4, c4 = e & 15;
      long gofs = (n0 + row) * 512 + h * 64 + c4 * 4;
      u16x4 kk = *reinterpret_cast<const u16x4*>(kq + gofs);
      u16x4 vv = *reinterpret_cast<const u16x4*>(vq + gofs);
      f32x4 kf = {b2f(kk[0]), b2f(kk[1]), b2f(kk[2]), b2f(kk[3])};
      f32x4 vf = {b2f(vv[0]), b2f(vv[1]), b2f(vv[2]), b2f(vv[3])};
      *reinterpret_cast<f32x4*>(&ks[row][c4 * 4]) = kf;
      *reinterpret_cast<f32x4*>(&vs[row][c4 * 4]) = vf;
    }
    __syncthreads();
#pragma unroll 4
    for (int n = 0; n < 32; ++n) {
      f32x4 kk = *reinterpret_cast<const f32x4*>(&ks[n][dk0]);
      f32x4 vv = *reinterpret_cast<const f32x4*>(&vs[n][dv0]);
#pragma unroll
      for (int a = 0; a < 4; ++a)
#pragma unroll
        for (int c = 0; c < 4; ++c)
          acc[a][c] += kk[a] * vv[c];
    }
    __syncthreads();
  }
  float* pg = part + ((long)chunk * 64 + bh) * 4096;
#pragma unroll
  for (int a = 0; a < 4; ++a) {
    f32x4 o = {acc[a][0], acc[a][1], acc[a][2], acc[a][3]};
    *reinterpret_cast<f32x4*>(pg + (dk0 + a) * 64 + dv0) = o;
  }
}

// reduce partials + L2-norm rows (over dv) * gamma -> kvn bf16 [bh][64][64]
__global__ __launch_bounds__(256)
void kv_normN(const float* __restrict__ part, const float* __restrict__ gamma,
              unsigned short* __restrict__ kvn) {
  const int bh = blockIdx.x, h = bh & 7;
  const int tid = threadIdx.x;
  __shared__ float kvs[4096];
  __shared__ float scale[64];
#pragma unroll
  for (int i = 0; i < 4; ++i) {
    int e4 = i * 256 + tid;
    const float* p = part + (long)bh * 4096 + e4 * 4;
    f32x4 s = {0.f, 0.f, 0.f, 0.f};
#pragma unroll
    for (int c = 0; c < NCHUNK; ++c) {
      f32x4 v = *reinterpret_cast<const f32x4*>(p + (long)c * 64 * 4096);
      s += v;
    }
    *reinterpret_cast<f32x4*>(kvs + e4 * 4) = s;
  }
  __syncthreads();
  if (tid < 64) {
    float s = 0.f;
    for (int dv = 0; dv < 64; ++dv) { float x = kvs[tid * 64 + dv]; s += x * x; }
    scale[tid] = gamma[h] / sqrtf(s);
  }
  __syncthreads();
#pragma unroll
  for (int i = 0; i < 4; ++i) {
    int e4 = i * 256 + tid;
    float sc = scale[e4 >> 4];
    f32x4 v = *reinterpret_cast<const f32x4*>(kvs + e4 * 4);
    u16x4 o = {f2b(v[0] * sc), f2b(v[1] * sc), f2b(v[2] * sc), f2b(v[3] * sc)};
    *reinterpret_cast<u16x4*>(kvn + (long)bh * 4096 + e4 * 4) = o;
  }
}

// Mt[b][c][h*64+dk] = sum_dv Wo[c][h*64+dv] * kvn[b,h][dk][dv]
__global__ __launch_bounds__(64)
void mt_kernel(const unsigned short* __restrict__ Wo_b,
               const unsigned short* __restrict__ kvn,
               unsigned short* __restrict__ Mt) {
  const int bid = blockIdx.x;
  const int bh = bid >> 2, seg = bid & 3;
  const int b = bh >> 3, h = bh & 7;
  const int lane = threadIdx.x;
  const int r = lane & 15, g = lane >> 4;
  f32x4 acc[8][4] = {};
  s16x8 bf[2][4];
#pragma unroll
  for (int ks = 0; ks < 2; ++ks)
#pragma unroll
    for (int j = 0; j < 4; ++j)
      bf[ks][j] = *reinterpret_cast<const s16x8*>(
          kvn + (long)bh * 4096 + (j * 16 + r) * 64 + ks * 32 + g * 8);
#pragma unroll
  for (int ks = 0; ks < 2; ++ks)
#pragma unroll
    for (int i = 0; i < 8; ++i) {
      s16x8 af = *reinterpret_cast<const s16x8*>(
          Wo_b + (long)(seg * 128 + i * 16 + r) * 512 + h * 64 + ks * 32 + g * 8);
#pragma unroll
      for (int j = 0; j < 4; ++j)
        acc[i][j] = __builtin_amdgcn_mfma_f32_16x16x32_bf16(af, bf[ks][j], acc[i][j], 0, 0, 0);
    }
#pragma unroll
  for (int i = 0; i < 8; ++i)
#pragma unroll
    for (int j = 0; j < 4; ++j)
#pragma unroll
      for (int ii = 0; ii < 4; ++ii) {
        int c = seg * 128 + i * 16 + g * 4 + ii;
        int dk = j * 16 + r;
        Mt[(long)b * 262144 + (long)c * 512 + h * 64 + dk] = f2b(acc[i][j][ii]);
      }
}

__global__ void cast4(const float* __restrict__ a0, const float* __restrict__ a1,
                      const float* __restrict__ a2, const float* __restrict__ a3,
                      unsigned short* __restrict__ o0, unsigned short* __restrict__ o1,
                      unsigned short* __restrict__ o2, unsigned short* __restrict__ o3) {
  const int y = blockIdx.y;
  const float* in = y == 0 ? a0 : (y == 1 ? a1 : (y == 2 ? a2 : a3));
  unsigned short* out = y == 0 ? o0 : (y == 1 ? o1 : (y == 2 ? o2 : o3));
  int i = blockIdx.x * 256 + threadIdx.x;
  f32x4 v = reinterpret_cast<const f32x4*>(in)[i];
  reinterpret_cast<u16x4*>(out)[i] = u16x4{f2b(v[0]), f2b(v[1]), f2b(v[2]), f2b(v[3])};
}

// ---------------------------------------------------------------------------
extern "C" void kernel_launch(void* const* d_in, const int* in_sizes, int n_in,
                              void* d_out, int out_size, void* d_ws, size_t ws_size,
                              hipStream_t stream) {
  const float* queries = (const float*)d_in[0];
  const float* keys    = (const float*)d_in[1];
  const float* values  = (const float*)d_in[2];
  const float* Wq = (const float*)d_in[3];
  const float* bq = (const float*)d_in[4];
  const float* Wk = (const float*)d_in[5];
  const float* bk = (const float*)d_in[6];
  const float* Wv = (const float*)d_in[7];
  const float* bv = (const float*)d_in[8];
  const float* Wo = (const float*)d_in[9];
  const float* bo = (const float*)d_in[10];
  const float* gamma = (const float*)d_in[11];

  unsigned short* Wq_b = (unsigned short*)d_ws;            // 512 KB each
  unsigned short* Wk_b = Wq_b + 262144;
  unsigned short* Wv_b = Wk_b + 262144;
  unsigned short* Wo_b = Wv_b + 262144;
  unsigned short* q_b  = Wo_b + 262144;                    // 32 MB (holds q_n)
  unsigned short* kvn  = q_b + 16777216;                   // 512 KB
  float* part = (float*)(kvn + 262144);                    // 16 MB
  unsigned short* Mt = (unsigned short*)part;              // 4 MB (part dead by then)
  unsigned short* k_b = (unsigned short*)d_out;            // d_out scratch
  unsigned short* v_b = k_b + 16777216;
  float* out = (float*)d_out;

  cast4<<<dim3(256, 4), 256, 0, stream>>>(Wq, Wk, Wv, Wo, Wq_b, Wk_b, Wv_b, Wo_b);

  proj_qkv<<<dim3(256, 3), 1024, 0, stream>>>(
      queries, keys, values, Wq_b, Wk_b, Wv_b, bq, bk, bv, q_b, k_b, v_b, gamma);

  kv_partial<<<dim3(NCHUNK, 64), 256, 0, stream>>>(k_b, v_b, part);
  kv_normN<<<64, 256, 0, stream>>>(part, gamma, kvn);
  mt_kernel<<<256, 64, 0, stream>>>(Wo_b, kvn, Mt);

  gemm_final<<<dim3(32, 8), 1024, 0, stream>>>(q_b, Mt, bo, out);
}